// Round 1
// baseline (1188.554 us; speedup 1.0000x reference)
//
#include <hip/hip_runtime.h>

typedef unsigned short u16;
typedef unsigned int u32;

typedef __attribute__((ext_vector_type(8))) short bf16x8;
typedef __attribute__((ext_vector_type(4))) float f32x4;

#define B_ 8
#define S_ 2048
#define H_ 8
#define ID_ 256
#define OD_ 256
#define K_ 512
#define M_ (B_*S_*H_)   /* 131072 */
#define N1_ 768
#define N2_ 256

// ---- workspace layout (bytes) ----
#define OFF_X2   (0ull)
#define SZ_X2    ((unsigned long long)M_*K_*2)        /* 134,217,728 */
#define OFF_G    (OFF_X2 + SZ_X2)
#define SZ_G     ((unsigned long long)M_*N1_*2)       /* 201,326,592 */
#define OFF_WH   (OFF_G + SZ_G)
#define SZ_WH    ((unsigned long long)N1_*K_*2)
#define OFF_WO   (OFF_WH + SZ_WH)
#define SZ_WO    ((unsigned long long)N2_*K_*2)
#define OFF_AUX  (OFF_WO + SZ_WO)
#define SZ_AUX   ((unsigned long long)B_*32*2048*4)
#define OFF_CF   (OFF_AUX + SZ_AUX)
#define SZ_CARR  ((unsigned long long)B_*H_*32*256*4)
#define OFF_CC   (OFF_CF + SZ_CARR)
#define OFF_CIN  (OFF_CC + SZ_CARR)

__device__ __forceinline__ u16 f2bf(float f) {
    union { float f; u32 u; } v; v.f = f;
    u32 u = v.u;
    u += 0x7fffu + ((u >> 16) & 1u);   // round-to-nearest-even
    return (u16)(u >> 16);
}
__device__ __forceinline__ float bf2f(u16 h) {
    union { u32 u; float f; } v; v.u = ((u32)h) << 16;
    return v.f;
}
__device__ __forceinline__ float sigm(float x) {
    return 1.0f / (1.0f + __expf(-x));
}

// ---- 0: weights fp32 -> bf16 ----
__global__ __launch_bounds__(256) void wconv_kernel(
    const float* __restrict__ Whid, const float* __restrict__ Wog,
    u16* __restrict__ WhB, u16* __restrict__ WoB)
{
    int idx = blockIdx.x * 256 + threadIdx.x;
    if (idx < N1_*K_) WhB[idx] = f2bf(Whid[idx]);
    if (idx < N2_*K_) WoB[idx] = f2bf(Wog[idx]);
}

// ---- 1: cumsum phase 1 — per-(b,chunk) local totals over 64 s-steps ----
// grid: B*32 blocks, 256 threads (t = d index); thread keeps 8 h-accumulators
__global__ __launch_bounds__(256) void csum_phase1(
    const float* __restrict__ X, float* __restrict__ aux)
{
    const int bch = blockIdx.x;          // b*32 + ch
    const int b = bch >> 5, ch = bch & 31;
    const int t = threadIdx.x;
    float acc[8];
#pragma unroll
    for (int h = 0; h < 8; ++h) acc[h] = 0.f;
    for (int i = 0; i < 64; ++i) {
        const int s = ch * 64 + i;
        const float* xp = X + ((size_t)(b * S_ + s)) * 2048 + t;
#pragma unroll
        for (int h = 0; h < 8; ++h) acc[h] += xp[h * 256];
    }
    float* ap = aux + (size_t)bch * 2048 + t;
#pragma unroll
    for (int h = 0; h < 8; ++h) ap[h * 256] = acc[h];
}

// ---- 2: cumsum carry — exclusive prefix over 32 chunks, in place ----
// grid: 64 blocks x 256 (16384 channels = B * 2048)
__global__ __launch_bounds__(256) void csum_mid(float* __restrict__ aux)
{
    const int idx = blockIdx.x * 256 + threadIdx.x;
    const int b = idx >> 11, c = idx & 2047;
    float run = 0.f;
    for (int ch = 0; ch < 32; ++ch) {
        float* p = aux + ((size_t)(b * 32 + ch)) * 2048 + c;
        float v = *p; *p = run; run += v;
    }
}

// ---- 3: cumsum phase 2 — replay + LayerNorm + pack x2 bf16 ----
// grid: B*32 blocks, 256 threads. Block holds all (h,d) channels for its (b,s),
// so LN stats (over H*ID=2048) are a block reduction.
__global__ __launch_bounds__(256) void csum_phase2(
    const float* __restrict__ X, const float* __restrict__ aux,
    const float* __restrict__ lnw, const float* __restrict__ lnb,
    u16* __restrict__ x2)
{
    const int bch = blockIdx.x;
    const int b = bch >> 5, ch = bch & 31;
    const int t = threadIdx.x;
    float c[8], wv[8], bv[8];
#pragma unroll
    for (int h = 0; h < 8; ++h) {
        c[h]  = aux[(size_t)bch * 2048 + h * 256 + t];
        wv[h] = lnw[h * 256 + t];
        bv[h] = lnb[h * 256 + t];
    }
    __shared__ float red[2][4];
    for (int i = 0; i < 64; ++i) {
        const int s = ch * 64 + i;
        const float* xp = X + ((size_t)(b * S_ + s)) * 2048 + t;
        float xa[8];
#pragma unroll
        for (int h = 0; h < 8; ++h) { xa[h] = xp[h * 256]; c[h] += xa[h]; }
        float sx = 0.f, sq = 0.f;
#pragma unroll
        for (int h = 0; h < 8; ++h) { sx += c[h]; sq += c[h] * c[h]; }
#pragma unroll
        for (int off = 32; off >= 1; off >>= 1) {
            sx += __shfl_down(sx, (unsigned)off);
            sq += __shfl_down(sq, (unsigned)off);
        }
        const int wid = t >> 6;
        if ((t & 63) == 0) { red[0][wid] = sx; red[1][wid] = sq; }
        __syncthreads();
        const float tsx = red[0][0] + red[0][1] + red[0][2] + red[0][3];
        const float tsq = red[1][0] + red[1][1] + red[1][2] + red[1][3];
        __syncthreads();
        const float mean = tsx * (1.f / 2048.f);
        const float var  = tsq * (1.f / 2048.f) - mean * mean;
        const float rstd = rsqrtf(var + 1e-6f);
        const size_t mrow = ((size_t)(b * S_ + s)) * H_;
#pragma unroll
        for (int h = 0; h < 8; ++h) {
            u16* row = x2 + (mrow + h) * (size_t)K_;
            row[t]       = f2bf(xa[h]);
            row[256 + t] = f2bf((c[h] - mean) * rstd * wv[h] + bv[h]);
        }
    }
}

// ---- GEMM: C[m,n] = sum_k A[m,k] * W[n,k], A/W bf16 row-major (ld=512) ----
// 128x128 block tile, BK=64, 4 waves in 2x2 each computing 64x64 via 4x4
// mfma_f32_16x16x32_bf16. LDS rows padded to 72 bf16 (144 B) -> 2-way-only
// bank aliasing on ds_read_b128 (free per m136).
template<int N, bool OG_EPI>
__global__ __launch_bounds__(256) void gemm_kernel(
    const u16* __restrict__ A, const u16* __restrict__ Bw,
    u16* __restrict__ Gout, const float* __restrict__ bias,
    const u16* __restrict__ cellbuf, float* __restrict__ Out)
{
    constexpr int NT = N / 128;
    const int tileM = blockIdx.x / NT;
    const int tileN = blockIdx.x % NT;
    const int m0 = tileM * 128, n0 = tileN * 128;
    const int tid = threadIdx.x;
    const int lane = tid & 63;
    const int w = tid >> 6, wm = w & 1, wn = w >> 1;
    const int l15 = lane & 15, quad = lane >> 4;

    __shared__ __align__(16) u16 As[128 * 72];
    __shared__ __align__(16) u16 Bs[128 * 72];

    const int cg = tid & 7;      // 16B column group within 64-wide k-slice
    const int r0 = tid >> 3;     // 0..31 base row

    f32x4 acc[4][4];
    const f32x4 zero4 = {0.f, 0.f, 0.f, 0.f};
#pragma unroll
    for (int i = 0; i < 4; ++i)
#pragma unroll
        for (int j = 0; j < 4; ++j) acc[i][j] = zero4;

    for (int kt = 0; kt < K_ / 64; ++kt) {
        const int k0 = kt * 64;
        uint4 av[4], bv[4];
#pragma unroll
        for (int p = 0; p < 4; ++p) {
            const int r = r0 + p * 32;
            av[p] = *(const uint4*)(const void*)(A  + (size_t)(m0 + r) * K_ + k0 + cg * 8);
            bv[p] = *(const uint4*)(const void*)(Bw + (size_t)(n0 + r) * K_ + k0 + cg * 8);
        }
        __syncthreads();   // previous iteration's LDS reads complete
#pragma unroll
        for (int p = 0; p < 4; ++p) {
            const int r = r0 + p * 32;
            *(uint4*)(void*)(&As[r * 72 + cg * 8]) = av[p];
            *(uint4*)(void*)(&Bs[r * 72 + cg * 8]) = bv[p];
        }
        __syncthreads();
#pragma unroll
        for (int kk = 0; kk < 2; ++kk) {
            bf16x8 af[4], bfr[4];
#pragma unroll
            for (int i = 0; i < 4; ++i) {
                const int rowa = wm * 64 + i * 16 + l15;
                const int rowb = wn * 64 + i * 16 + l15;
                af[i]  = *(const bf16x8*)(const void*)(&As[rowa * 72 + kk * 32 + quad * 8]);
                bfr[i] = *(const bf16x8*)(const void*)(&Bs[rowb * 72 + kk * 32 + quad * 8]);
            }
#pragma unroll
            for (int i = 0; i < 4; ++i)
#pragma unroll
                for (int j = 0; j < 4; ++j)
                    acc[i][j] = __builtin_amdgcn_mfma_f32_16x16x32_bf16(
                        af[i], bfr[j], acc[i][j], 0, 0, 0);
        }
    }

    // epilogue: C/D layout col=lane&15, row=quad*4+reg (m89-verified)
#pragma unroll
    for (int i = 0; i < 4; ++i) {
        const int rowbase = m0 + wm * 64 + i * 16 + quad * 4;
#pragma unroll
        for (int j = 0; j < 4; ++j) {
            const int col = n0 + wn * 64 + j * 16 + l15;
#pragma unroll
            for (int r = 0; r < 4; ++r) {
                const int row = rowbase + r;
                if (!OG_EPI) {
                    Gout[(size_t)row * N + col] = f2bf(acc[i][j][r]);
                } else {
                    const float pre = acc[i][j][r] + bias[col];
                    const float og = sigm(pre);
                    const float cell = bf2f(cellbuf[(size_t)row * K_ + 256 + col]);
                    Out[(size_t)row * N2_ + col] = og * cell;
                }
            }
        }
    }
}

// ---- scan phase 1: per-(b,h,chunk) local recurrence over 64 steps ----
// c = f*c + igh with c_in = 0; also F = prod f. grid: B*H*32 blocks, 256 thr.
__global__ __launch_bounds__(256) void scan_phase1(
    const u16* __restrict__ g, const float* __restrict__ bhid,
    float* __restrict__ cF, float* __restrict__ cC)
{
    const int blk = blockIdx.x;              // (b*8+h)*32 + ch
    const int ch = blk & 31, bh = blk >> 5;
    const int h = bh & 7, b = bh >> 3;
    const int o = threadIdx.x;
    const float bi = bhid[o], bfg = bhid[256 + o], bhd = bhid[512 + o];
    float F = 1.f, c = 0.f;
    for (int i = 0; i < 64; ++i) {
        const int s = ch * 64 + i;
        const size_t m = ((size_t)(b * S_ + s)) * H_ + h;
        const u16* gp = g + m * N1_;
        const float ig = bf2f(gp[o]) + bi;
        const float fg = bf2f(gp[256 + o]) + bfg;
        const float hd = bf2f(gp[512 + o]) + bhd;
        const float f = sigm(fg);
        const float igh = sigm(ig) * fmaxf(hd, 0.f);
        c = f * c + igh;
        F *= f;
    }
    cF[(size_t)blk * 256 + o] = F;
    cC[(size_t)blk * 256 + o] = c;
}

// ---- scan carry combine: sequential over 32 chunks per (b,h,o) ----
__global__ __launch_bounds__(256) void scan_mid(
    const float* __restrict__ cF, const float* __restrict__ cC,
    const float* __restrict__ initcx, float* __restrict__ cin)
{
    const int bh = blockIdx.x;               // b*8 + h
    const int h = bh & 7;
    const int o = threadIdx.x;
    float c = initcx[h * 256 + o];
    for (int ch = 0; ch < 32; ++ch) {
        const size_t idx = ((size_t)(bh * 32 + ch)) * 256 + o;
        cin[idx] = c;
        c = cF[idx] * c + cC[idx];
    }
}

// ---- scan phase 2: replay with true carry-in; write cell bf16 into x2 ----
// (overwrites x2 cols [256,512) — GEMM1 already consumed them)
__global__ __launch_bounds__(256) void scan_phase2(
    const u16* __restrict__ g, const float* __restrict__ bhid,
    const float* __restrict__ cin, u16* __restrict__ x2)
{
    const int blk = blockIdx.x;
    const int ch = blk & 31, bh = blk >> 5;
    const int h = bh & 7, b = bh >> 3;
    const int o = threadIdx.x;
    const float bi = bhid[o], bfg = bhid[256 + o], bhd = bhid[512 + o];
    float c = cin[(size_t)blk * 256 + o];
    for (int i = 0; i < 64; ++i) {
        const int s = ch * 64 + i;
        const size_t m = ((size_t)(b * S_ + s)) * H_ + h;
        const u16* gp = g + m * N1_;
        const float ig = bf2f(gp[o]) + bi;
        const float fg = bf2f(gp[256 + o]) + bfg;
        const float hd = bf2f(gp[512 + o]) + bhd;
        const float f = sigm(fg);
        const float igh = sigm(ig) * fmaxf(hd, 0.f);
        c = f * c + igh;
        x2[m * K_ + 256 + o] = f2bf(c);
    }
}

extern "C" void kernel_launch(void* const* d_in, const int* in_sizes, int n_in,
                              void* d_out, int out_size, void* d_ws, size_t ws_size,
                              hipStream_t stream)
{
    const float* X      = (const float*)d_in[0];
    const float* Whid   = (const float*)d_in[1];
    const float* bhid   = (const float*)d_in[2];
    const float* Wog    = (const float*)d_in[3];
    const float* bog    = (const float*)d_in[4];
    const float* lnw    = (const float*)d_in[5];
    const float* lnb    = (const float*)d_in[6];
    const float* initcx = (const float*)d_in[7];
    float* out = (float*)d_out;

    char* ws = (char*)d_ws;
    u16* x2   = (u16*)(ws + OFF_X2);
    u16* g    = (u16*)(ws + OFF_G);
    u16* WhB  = (u16*)(ws + OFF_WH);
    u16* WoB  = (u16*)(ws + OFF_WO);
    float* aux = (float*)(ws + OFF_AUX);
    float* cF  = (float*)(ws + OFF_CF);
    float* cC  = (float*)(ws + OFF_CC);
    float* cin = (float*)(ws + OFF_CIN);

    wconv_kernel<<<(N1_*K_ + 255) / 256, 256, 0, stream>>>(Whid, Wog, WhB, WoB);
    csum_phase1<<<B_ * 32, 256, 0, stream>>>(X, aux);
    csum_mid<<<64, 256, 0, stream>>>(aux);
    csum_phase2<<<B_ * 32, 256, 0, stream>>>(X, aux, lnw, lnb, x2);
    gemm_kernel<N1_, false><<<(M_ / 128) * (N1_ / 128), 256, 0, stream>>>(
        x2, WhB, g, nullptr, nullptr, nullptr);
    scan_phase1<<<B_ * H_ * 32, 256, 0, stream>>>(g, bhid, cF, cC);
    scan_mid<<<B_ * H_, 256, 0, stream>>>(cF, cC, initcx, cin);
    scan_phase2<<<B_ * H_ * 32, 256, 0, stream>>>(g, bhid, cin, x2);
    gemm_kernel<N2_, true><<<(M_ / 128) * (N2_ / 128), 256, 0, stream>>>(
        x2, WoB, nullptr, bog, x2, out);
}

// Round 2
// 1178.448 us; speedup vs baseline: 1.0086x; 1.0086x over previous
//
#include <hip/hip_runtime.h>

typedef unsigned short u16;
typedef unsigned int u32;

typedef __attribute__((ext_vector_type(8))) short bf16x8;
typedef __attribute__((ext_vector_type(4))) float f32x4;

#define B_ 8
#define S_ 2048
#define H_ 8
#define ID_ 256
#define OD_ 256
#define K_ 512
#define M_ (B_*S_*H_)   /* 131072 */
#define N1_ 768
#define N2_ 256

#define CSCH 64            /* cumsum chunks over S */
#define CSST (S_/CSCH)     /* 32 steps per chunk */

// ---- workspace layout (bytes) ----
#define OFF_X2   (0ull)
#define SZ_X2    ((unsigned long long)M_*K_*2)        /* 134,217,728 */
#define OFF_G    (OFF_X2 + SZ_X2)
#define SZ_G     ((unsigned long long)M_*N1_*2)       /* 201,326,592 */
#define OFF_WH   (OFF_G + SZ_G)
#define SZ_WH    ((unsigned long long)N1_*K_*2)
#define OFF_WO   (OFF_WH + SZ_WH)
#define SZ_WO    ((unsigned long long)N2_*K_*2)
#define OFF_AUX  (OFF_WO + SZ_WO)
#define SZ_AUX   ((unsigned long long)B_*CSCH*2048*4)
#define OFF_CF   (OFF_AUX + SZ_AUX)
#define SZ_CARR  ((unsigned long long)B_*H_*32*256*4)
#define OFF_CC   (OFF_CF + SZ_CARR)
#define OFF_CIN  (OFF_CC + SZ_CARR)

__device__ __forceinline__ u16 f2bf(float f) {
    union { float f; u32 u; } v; v.f = f;
    u32 u = v.u;
    u += 0x7fffu + ((u >> 16) & 1u);   // round-to-nearest-even
    return (u16)(u >> 16);
}
__device__ __forceinline__ float bf2f(u16 h) {
    union { u32 u; float f; } v; v.u = ((u32)h) << 16;
    return v.f;
}
__device__ __forceinline__ float sigm(float x) {
    return 1.0f / (1.0f + __expf(-x));
}

// ---- 0: weights fp32 -> bf16 ----
__global__ __launch_bounds__(256) void wconv_kernel(
    const float* __restrict__ Whid, const float* __restrict__ Wog,
    u16* __restrict__ WhB, u16* __restrict__ WoB)
{
    int idx = blockIdx.x * 256 + threadIdx.x;
    if (idx < N1_*K_) WhB[idx] = f2bf(Whid[idx]);
    if (idx < N2_*K_) WoB[idx] = f2bf(Wog[idx]);
}

// ---- 1: cumsum phase 1 — per-(b,chunk) local totals over CSST s-steps ----
__global__ __launch_bounds__(256) void csum_phase1(
    const float* __restrict__ X, float* __restrict__ aux)
{
    const int bch = blockIdx.x;          // b*CSCH + ch
    const int b = bch / CSCH, ch = bch % CSCH;
    const int t = threadIdx.x;
    float acc[8];
#pragma unroll
    for (int h = 0; h < 8; ++h) acc[h] = 0.f;
    for (int i = 0; i < CSST; ++i) {
        const int s = ch * CSST + i;
        const float* xp = X + ((size_t)(b * S_ + s)) * 2048 + t;
#pragma unroll
        for (int h = 0; h < 8; ++h) acc[h] += xp[h * 256];
    }
    float* ap = aux + (size_t)bch * 2048 + t;
#pragma unroll
    for (int h = 0; h < 8; ++h) ap[h * 256] = acc[h];
}

// ---- 2: cumsum carry — exclusive prefix over CSCH chunks, in place ----
__global__ __launch_bounds__(256) void csum_mid(float* __restrict__ aux)
{
    const int idx = blockIdx.x * 256 + threadIdx.x;
    const int b = idx >> 11, c = idx & 2047;
    float run = 0.f;
    for (int ch = 0; ch < CSCH; ++ch) {
        float* p = aux + ((size_t)(b * CSCH + ch)) * 2048 + c;
        float v = *p; *p = run; run += v;
    }
}

// ---- 3: cumsum phase 2 — replay + LayerNorm + pack x2 bf16 ----
__global__ __launch_bounds__(256) void csum_phase2(
    const float* __restrict__ X, const float* __restrict__ aux,
    const float* __restrict__ lnw, const float* __restrict__ lnb,
    u16* __restrict__ x2)
{
    const int bch = blockIdx.x;
    const int b = bch / CSCH, ch = bch % CSCH;
    const int t = threadIdx.x;
    float c[8], wv[8], bv[8];
#pragma unroll
    for (int h = 0; h < 8; ++h) {
        c[h]  = aux[(size_t)bch * 2048 + h * 256 + t];
        wv[h] = lnw[h * 256 + t];
        bv[h] = lnb[h * 256 + t];
    }
    __shared__ float red[2][4];
    for (int i = 0; i < CSST; ++i) {
        const int s = ch * CSST + i;
        const float* xp = X + ((size_t)(b * S_ + s)) * 2048 + t;
        float xa[8];
#pragma unroll
        for (int h = 0; h < 8; ++h) { xa[h] = xp[h * 256]; c[h] += xa[h]; }
        float sx = 0.f, sq = 0.f;
#pragma unroll
        for (int h = 0; h < 8; ++h) { sx += c[h]; sq += c[h] * c[h]; }
#pragma unroll
        for (int off = 32; off >= 1; off >>= 1) {
            sx += __shfl_down(sx, (unsigned)off);
            sq += __shfl_down(sq, (unsigned)off);
        }
        const int wid = t >> 6;
        if ((t & 63) == 0) { red[0][wid] = sx; red[1][wid] = sq; }
        __syncthreads();
        const float tsx = red[0][0] + red[0][1] + red[0][2] + red[0][3];
        const float tsq = red[1][0] + red[1][1] + red[1][2] + red[1][3];
        __syncthreads();
        const float mean = tsx * (1.f / 2048.f);
        const float var  = tsq * (1.f / 2048.f) - mean * mean;
        const float rstd = rsqrtf(var + 1e-6f);
        const size_t mrow = ((size_t)(b * S_ + s)) * H_;
#pragma unroll
        for (int h = 0; h < 8; ++h) {
            u16* row = x2 + (mrow + h) * (size_t)K_;
            row[t]       = f2bf(xa[h]);
            row[256 + t] = f2bf((c[h] - mean) * rstd * wv[h] + bv[h]);
        }
    }
}

// ---- GEMM: C[m,n] = sum_k A[m,k] * W[n,k], A/W bf16 row-major (ld=512) ----
// 128x128 tile, BK=64, 4 waves (2x2) x 64x64 each via 4x4 mfma_16x16x32_bf16.
// LDS: unpadded 64-col rows with XOR-16B-chunk swizzle (phys = c ^ (row&7)).
// Tile->block mapping is XCD-aware (blockIdx%8 assumed = XCD): all N-tiles of
// one M-tile land on one XCD for A-tile L2 reuse.
// Epilogue stages C through LDS (reusing As/Bs) for coalesced global writes.
template<int N, bool OG_EPI>
__global__ __launch_bounds__(256) void gemm_kernel(
    const u16* __restrict__ A, const u16* __restrict__ Bw,
    u16* __restrict__ Gout, const float* __restrict__ bias,
    const u16* __restrict__ cellbuf, float* __restrict__ Out)
{
    constexpr int NT = N / 128;
    const int blk = blockIdx.x;
    const int xcd = blk & 7;
    const int j = blk >> 3;
    const int tileN = j % NT;
    const int tileM = (j / NT) * 8 + xcd;
    const int m0 = tileM * 128, n0 = tileN * 128;
    const int tid = threadIdx.x;
    const int lane = tid & 63;
    const int w = tid >> 6, wm = w & 1, wn = w >> 1;
    const int l15 = lane & 15, quad = lane >> 4;

    __shared__ __align__(16) u16 smem[2 * 128 * 64];   // 32 KB
    u16* As = smem;
    u16* Bs = smem + 128 * 64;

    const int cg = tid & 7;      // 16B chunk within 64-wide k-slice
    const int r0 = tid >> 3;     // 0..31 base row
    const int scg = cg ^ (r0 & 7);       // swizzled store chunk
    const int ra7 = l15 & 7;             // row&7 for fragment reads

    f32x4 acc[4][4];
    const f32x4 zero4 = {0.f, 0.f, 0.f, 0.f};
#pragma unroll
    for (int i = 0; i < 4; ++i)
#pragma unroll
        for (int jj = 0; jj < 4; ++jj) acc[i][jj] = zero4;

    for (int kt = 0; kt < K_ / 64; ++kt) {
        const int k0 = kt * 64;
        uint4 av[4], bv[4];
#pragma unroll
        for (int p = 0; p < 4; ++p) {
            const int r = r0 + p * 32;
            av[p] = *(const uint4*)(const void*)(A  + (size_t)(m0 + r) * K_ + k0 + cg * 8);
            bv[p] = *(const uint4*)(const void*)(Bw + (size_t)(n0 + r) * K_ + k0 + cg * 8);
        }
        __syncthreads();   // previous iteration's LDS reads complete
#pragma unroll
        for (int p = 0; p < 4; ++p) {
            const int r = r0 + p * 32;
            *(uint4*)(void*)(&As[r * 64 + scg * 8]) = av[p];
            *(uint4*)(void*)(&Bs[r * 64 + scg * 8]) = bv[p];
        }
        __syncthreads();
#pragma unroll
        for (int kk = 0; kk < 2; ++kk) {
            bf16x8 af[4], bfr[4];
#pragma unroll
            for (int i = 0; i < 4; ++i) {
                const int rowa = wm * 64 + i * 16 + l15;
                const int rowb = wn * 64 + i * 16 + l15;
                const int ca = ((kk * 4 + quad) ^ ra7) * 8;
                af[i]  = *(const bf16x8*)(const void*)(&As[rowa * 64 + ca]);
                bfr[i] = *(const bf16x8*)(const void*)(&Bs[rowb * 64 + ca]);
            }
#pragma unroll
            for (int i = 0; i < 4; ++i)
#pragma unroll
                for (int jj = 0; jj < 4; ++jj)
                    acc[i][jj] = __builtin_amdgcn_mfma_f32_16x16x32_bf16(
                        af[i], bfr[jj], acc[i][jj], 0, 0, 0);
        }
    }

    // ---- epilogue (C/D layout: col=lane&15, row=quad*4+reg) ----
    __syncthreads();   // all LDS fragment reads done; safe to reuse smem
    if (!OG_EPI) {
        // stage bf16 tile 128x128 in smem, then coalesced 16B stores
        u16* Cs = smem;
#pragma unroll
        for (int i = 0; i < 4; ++i) {
            const int lrow0 = wm * 64 + i * 16 + quad * 4;
#pragma unroll
            for (int jj = 0; jj < 4; ++jj) {
                const int col = wn * 64 + jj * 16 + l15;
#pragma unroll
                for (int r = 0; r < 4; ++r)
                    Cs[(lrow0 + r) * 128 + col] = f2bf(acc[i][jj][r]);
            }
        }
        __syncthreads();
#pragma unroll
        for (int p = 0; p < 8; ++p) {
            const int row = p * 16 + (tid >> 4);
            const int ch16 = tid & 15;
            uint4 v = *(const uint4*)(const void*)(&Cs[row * 128 + ch16 * 8]);
            *(uint4*)(void*)(Gout + (size_t)(m0 + row) * N + n0 + ch16 * 8) = v;
        }
    } else {
        // fp32 out with sigmoid(x+b)*cell; stage 64 rows at a time
        float* Cf = (float*)smem;           // 64 x 128 fp32 = 32 KB
        const int col4 = (tid & 31) * 4;    // output col group for write pass
        float4 b4 = *(const float4*)(const void*)(bias + n0 + col4);
#pragma unroll
        for (int half = 0; half < 2; ++half) {
            if (wm == half) {
#pragma unroll
                for (int i = 0; i < 4; ++i) {
                    const int lrow0 = i * 16 + quad * 4;
#pragma unroll
                    for (int jj = 0; jj < 4; ++jj) {
                        const int col = wn * 64 + jj * 16 + l15;
#pragma unroll
                        for (int r = 0; r < 4; ++r)
                            Cf[(lrow0 + r) * 128 + col] = acc[i][jj][r];
                    }
                }
            }
            __syncthreads();
#pragma unroll
            for (int q = 0; q < 8; ++q) {
                const int lrow = q * 8 + (tid >> 5);
                const int grow = m0 + half * 64 + lrow;
                float4 v = *(const float4*)(const void*)(&Cf[lrow * 128 + col4]);
                const u16* cp = cellbuf + (size_t)grow * K_ + 256 + n0 + col4;
                float4 o;
                o.x = sigm(v.x + b4.x) * bf2f(cp[0]);
                o.y = sigm(v.y + b4.y) * bf2f(cp[1]);
                o.z = sigm(v.z + b4.z) * bf2f(cp[2]);
                o.w = sigm(v.w + b4.w) * bf2f(cp[3]);
                *(float4*)(void*)(Out + (size_t)grow * N2_ + n0 + col4) = o;
            }
            __syncthreads();
        }
    }
}

// ---- scan phase 1: per-(b,h,chunk) local recurrence over 64 steps ----
__global__ __launch_bounds__(256) void scan_phase1(
    const u16* __restrict__ g, const float* __restrict__ bhid,
    float* __restrict__ cF, float* __restrict__ cC)
{
    const int blk = blockIdx.x;              // (b*8+h)*32 + ch
    const int ch = blk & 31, bh = blk >> 5;
    const int h = bh & 7, b = bh >> 3;
    const int o = threadIdx.x;
    const float bi = bhid[o], bfg = bhid[256 + o], bhd = bhid[512 + o];
    float F = 1.f, c = 0.f;
    for (int i = 0; i < 64; ++i) {
        const int s = ch * 64 + i;
        const size_t m = ((size_t)(b * S_ + s)) * H_ + h;
        const u16* gp = g + m * N1_;
        const float ig = bf2f(gp[o]) + bi;
        const float fg = bf2f(gp[256 + o]) + bfg;
        const float hd = bf2f(gp[512 + o]) + bhd;
        const float f = sigm(fg);
        const float igh = sigm(ig) * fmaxf(hd, 0.f);
        c = f * c + igh;
        F *= f;
    }
    cF[(size_t)blk * 256 + o] = F;
    cC[(size_t)blk * 256 + o] = c;
}

// ---- scan carry combine ----
__global__ __launch_bounds__(256) void scan_mid(
    const float* __restrict__ cF, const float* __restrict__ cC,
    const float* __restrict__ initcx, float* __restrict__ cin)
{
    const int bh = blockIdx.x;               // b*8 + h
    const int h = bh & 7;
    const int o = threadIdx.x;
    float c = initcx[h * 256 + o];
    for (int ch = 0; ch < 32; ++ch) {
        const size_t idx = ((size_t)(bh * 32 + ch)) * 256 + o;
        cin[idx] = c;
        c = cF[idx] * c + cC[idx];
    }
}

// ---- scan phase 2: replay; write cell bf16 into x2 cols [256,512) ----
__global__ __launch_bounds__(256) void scan_phase2(
    const u16* __restrict__ g, const float* __restrict__ bhid,
    const float* __restrict__ cin, u16* __restrict__ x2)
{
    const int blk = blockIdx.x;
    const int ch = blk & 31, bh = blk >> 5;
    const int h = bh & 7, b = bh >> 3;
    const int o = threadIdx.x;
    const float bi = bhid[o], bfg = bhid[256 + o], bhd = bhid[512 + o];
    float c = cin[(size_t)blk * 256 + o];
    for (int i = 0; i < 64; ++i) {
        const int s = ch * 64 + i;
        const size_t m = ((size_t)(b * S_ + s)) * H_ + h;
        const u16* gp = g + m * N1_;
        const float ig = bf2f(gp[o]) + bi;
        const float fg = bf2f(gp[256 + o]) + bfg;
        const float hd = bf2f(gp[512 + o]) + bhd;
        const float f = sigm(fg);
        const float igh = sigm(ig) * fmaxf(hd, 0.f);
        c = f * c + igh;
        x2[m * K_ + 256 + o] = f2bf(c);
    }
}

extern "C" void kernel_launch(void* const* d_in, const int* in_sizes, int n_in,
                              void* d_out, int out_size, void* d_ws, size_t ws_size,
                              hipStream_t stream)
{
    const float* X      = (const float*)d_in[0];
    const float* Whid   = (const float*)d_in[1];
    const float* bhid   = (const float*)d_in[2];
    const float* Wog    = (const float*)d_in[3];
    const float* bog    = (const float*)d_in[4];
    const float* lnw    = (const float*)d_in[5];
    const float* lnb    = (const float*)d_in[6];
    const float* initcx = (const float*)d_in[7];
    float* out = (float*)d_out;

    char* ws = (char*)d_ws;
    u16* x2   = (u16*)(ws + OFF_X2);
    u16* g    = (u16*)(ws + OFF_G);
    u16* WhB  = (u16*)(ws + OFF_WH);
    u16* WoB  = (u16*)(ws + OFF_WO);
    float* aux = (float*)(ws + OFF_AUX);
    float* cF  = (float*)(ws + OFF_CF);
    float* cC  = (float*)(ws + OFF_CC);
    float* cin = (float*)(ws + OFF_CIN);

    wconv_kernel<<<(N1_*K_ + 255) / 256, 256, 0, stream>>>(Whid, Wog, WhB, WoB);
    csum_phase1<<<B_ * CSCH, 256, 0, stream>>>(X, aux);
    csum_mid<<<64, 256, 0, stream>>>(aux);
    csum_phase2<<<B_ * CSCH, 256, 0, stream>>>(X, aux, lnw, lnb, x2);
    gemm_kernel<N1_, false><<<(M_ / 128) * (N1_ / 128), 256, 0, stream>>>(
        x2, WhB, g, nullptr, nullptr, nullptr);
    scan_phase1<<<B_ * H_ * 32, 256, 0, stream>>>(g, bhid, cF, cC);
    scan_mid<<<B_ * H_, 256, 0, stream>>>(cF, cC, initcx, cin);
    scan_phase2<<<B_ * H_ * 32, 256, 0, stream>>>(g, bhid, cin, x2);
    gemm_kernel<N2_, true><<<(M_ / 128) * (N2_ / 128), 256, 0, stream>>>(
        x2, WoB, nullptr, bog, x2, out);
}

// Round 3
// 643.543 us; speedup vs baseline: 1.8469x; 1.8312x over previous
//
#include <hip/hip_runtime.h>

typedef unsigned short u16;
typedef unsigned int u32;

typedef __attribute__((ext_vector_type(8))) short bf16x8;
typedef __attribute__((ext_vector_type(4))) float f32x4;

#define B_ 8
#define S_ 2048
#define H_ 8
#define ID_ 256
#define OD_ 256
#define K_ 512
#define M_ (B_*S_*H_)   /* 131072 */
#define N1_ 768
#define N2_ 256

#define CSCH 64            /* cumsum chunks over S */
#define CSST (S_/CSCH)     /* 32 steps per chunk */

// ---- workspace layout (bytes) ----
#define OFF_X2   (0ull)
#define SZ_X2    ((unsigned long long)M_*K_*2)        /* 134,217,728 */
#define OFF_G    (OFF_X2 + SZ_X2)
#define SZ_G     ((unsigned long long)M_*N1_*2)       /* 201,326,592 */
#define OFF_WH   (OFF_G + SZ_G)
#define SZ_WH    ((unsigned long long)N1_*K_*2)
#define OFF_WO   (OFF_WH + SZ_WH)
#define SZ_WO    ((unsigned long long)N2_*K_*2)
#define OFF_AUX  (OFF_WO + SZ_WO)
#define SZ_AUX   ((unsigned long long)B_*CSCH*2048*4)
#define OFF_CF   (OFF_AUX + SZ_AUX)
#define SZ_CARR  ((unsigned long long)B_*H_*32*256*4)
#define OFF_CC   (OFF_CF + SZ_CARR)
#define OFF_CIN  (OFF_CC + SZ_CARR)

__device__ __forceinline__ u16 f2bf(float f) {
    union { float f; u32 u; } v; v.f = f;
    u32 u = v.u;
    u += 0x7fffu + ((u >> 16) & 1u);   // round-to-nearest-even
    return (u16)(u >> 16);
}
__device__ __forceinline__ float bf2f(u16 h) {
    union { u32 u; float f; } v; v.u = ((u32)h) << 16;
    return v.f;
}
__device__ __forceinline__ float sigm(float x) {
    return 1.0f / (1.0f + __expf(-x));
}

// async 16B global->LDS DMA. LDS dest = wave-uniform base + lane*16.
__device__ __forceinline__ void gld16(const void* g, void* l) {
    __builtin_amdgcn_global_load_lds(
        (const __attribute__((address_space(1))) void*)g,
        (__attribute__((address_space(3))) void*)l, 16, 0, 0);
}

// ---- 0: weights fp32 -> bf16 ----
__global__ __launch_bounds__(256) void wconv_kernel(
    const float* __restrict__ Whid, const float* __restrict__ Wog,
    u16* __restrict__ WhB, u16* __restrict__ WoB)
{
    int idx = blockIdx.x * 256 + threadIdx.x;
    if (idx < N1_*K_) WhB[idx] = f2bf(Whid[idx]);
    if (idx < N2_*K_) WoB[idx] = f2bf(Wog[idx]);
}

// ---- 1: cumsum phase 1 — per-(b,chunk) local totals over CSST s-steps ----
__global__ __launch_bounds__(256) void csum_phase1(
    const float* __restrict__ X, float* __restrict__ aux)
{
    const int bch = blockIdx.x;          // b*CSCH + ch
    const int b = bch / CSCH, ch = bch % CSCH;
    const int t = threadIdx.x;
    float acc[8];
#pragma unroll
    for (int h = 0; h < 8; ++h) acc[h] = 0.f;
    for (int i = 0; i < CSST; ++i) {
        const int s = ch * CSST + i;
        const float* xp = X + ((size_t)(b * S_ + s)) * 2048 + t;
#pragma unroll
        for (int h = 0; h < 8; ++h) acc[h] += xp[h * 256];
    }
    float* ap = aux + (size_t)bch * 2048 + t;
#pragma unroll
    for (int h = 0; h < 8; ++h) ap[h * 256] = acc[h];
}

// ---- 2: cumsum carry — exclusive prefix over CSCH chunks, in place ----
__global__ __launch_bounds__(256) void csum_mid(float* __restrict__ aux)
{
    const int idx = blockIdx.x * 256 + threadIdx.x;
    const int b = idx >> 11, c = idx & 2047;
    float run = 0.f;
    for (int ch = 0; ch < CSCH; ++ch) {
        float* p = aux + ((size_t)(b * CSCH + ch)) * 2048 + c;
        float v = *p; *p = run; run += v;
    }
}

// ---- 3: cumsum phase 2 — replay + LayerNorm + pack x2 bf16 ----
__global__ __launch_bounds__(256) void csum_phase2(
    const float* __restrict__ X, const float* __restrict__ aux,
    const float* __restrict__ lnw, const float* __restrict__ lnb,
    u16* __restrict__ x2)
{
    const int bch = blockIdx.x;
    const int b = bch / CSCH, ch = bch % CSCH;
    const int t = threadIdx.x;
    float c[8], wv[8], bv[8];
#pragma unroll
    for (int h = 0; h < 8; ++h) {
        c[h]  = aux[(size_t)bch * 2048 + h * 256 + t];
        wv[h] = lnw[h * 256 + t];
        bv[h] = lnb[h * 256 + t];
    }
    __shared__ float red[2][4];
    for (int i = 0; i < CSST; ++i) {
        const int s = ch * CSST + i;
        const float* xp = X + ((size_t)(b * S_ + s)) * 2048 + t;
        float xa[8];
#pragma unroll
        for (int h = 0; h < 8; ++h) { xa[h] = xp[h * 256]; c[h] += xa[h]; }
        float sx = 0.f, sq = 0.f;
#pragma unroll
        for (int h = 0; h < 8; ++h) { sx += c[h]; sq += c[h] * c[h]; }
#pragma unroll
        for (int off = 32; off >= 1; off >>= 1) {
            sx += __shfl_down(sx, (unsigned)off);
            sq += __shfl_down(sq, (unsigned)off);
        }
        const int wid = t >> 6;
        if ((t & 63) == 0) { red[0][wid] = sx; red[1][wid] = sq; }
        __syncthreads();
        const float tsx = red[0][0] + red[0][1] + red[0][2] + red[0][3];
        const float tsq = red[1][0] + red[1][1] + red[1][2] + red[1][3];
        __syncthreads();
        const float mean = tsx * (1.f / 2048.f);
        const float var  = tsq * (1.f / 2048.f) - mean * mean;
        const float rstd = rsqrtf(var + 1e-6f);
        const size_t mrow = ((size_t)(b * S_ + s)) * H_;
#pragma unroll
        for (int h = 0; h < 8; ++h) {
            u16* row = x2 + (mrow + h) * (size_t)K_;
            row[t]       = f2bf(xa[h]);
            row[256 + t] = f2bf((c[h] - mean) * rstd * wv[h] + bv[h]);
        }
    }
}

// ---- GEMM: C[m,n] = sum_k A[m,k] * W[n,k], A/W bf16 row-major (ld=512) ----
// 128x128 tile, BK=64, 4 waves (2x2) x 64x64 each via 4x4 mfma_16x16x32_bf16.
// Staging via async global_load_lds (16B/lane): LDS dest is forced contiguous
// (base+lane*16), so the XOR-16B-chunk conflict swizzle is applied on the
// GLOBAL address side (a permutation within the same 128B segment — free).
// Logical (row r, chunk c) lives at LDS phys r*128B + (c^(r&7))*16B.
template<int N, bool OG_EPI>
__global__ __launch_bounds__(256) void gemm_kernel(
    const u16* __restrict__ A, const u16* __restrict__ Bw,
    u16* __restrict__ Gout, const float* __restrict__ bias,
    const u16* __restrict__ cellbuf, float* __restrict__ Out)
{
    constexpr int NT = N / 128;
    const int blk = blockIdx.x;
    const int xcd = blk & 7;
    const int j = blk >> 3;
    const int tileN = j % NT;
    const int tileM = (j / NT) * 8 + xcd;
    const int m0 = tileM * 128, n0 = tileN * 128;
    const int tid = threadIdx.x;
    const int lane = tid & 63;
    const int w = tid >> 6, wm = w & 1, wn = w >> 1;
    const int l15 = lane & 15, quad = lane >> 4;

    __shared__ __align__(16) u16 smem[2 * 128 * 64];   // 32 KB
    u16* As = smem;
    u16* Bs = smem + 128 * 64;

    const int lane3 = lane >> 3;   // row-within-8-group
    const int pc = lane & 7;       // physical 16B chunk
    const int ra7 = l15 & 7;       // row&7 for fragment reads

    f32x4 acc[4][4];
    const f32x4 zero4 = {0.f, 0.f, 0.f, 0.f};
#pragma unroll
    for (int i = 0; i < 4; ++i)
#pragma unroll
        for (int jj = 0; jj < 4; ++jj) acc[i][jj] = zero4;

    for (int kt = 0; kt < K_ / 64; ++kt) {
        const int k0 = kt * 64;
        // issue async DMA for this tile (LDS free: post-compute barrier of
        // previous iteration has already passed)
#pragma unroll
        for (int p = 0; p < 4; ++p) {
            const int R0 = w * 32 + p * 8;
            const int r = R0 + lane3;
            const int ca = (pc ^ (r & 7)) * 8;     // swizzled logical chunk
            gld16(A  + (size_t)(m0 + r) * K_ + k0 + ca, As + R0 * 64);
            gld16(Bw + (size_t)(n0 + r) * K_ + k0 + ca, Bs + R0 * 64);
        }
        asm volatile("s_waitcnt vmcnt(0)" ::: "memory");
        __syncthreads();
#pragma unroll
        for (int kk = 0; kk < 2; ++kk) {
            bf16x8 af[4], bfr[4];
#pragma unroll
            for (int i = 0; i < 4; ++i) {
                const int rowa = wm * 64 + i * 16 + l15;
                const int rowb = wn * 64 + i * 16 + l15;
                const int ca = ((kk * 4 + quad) ^ ra7) * 8;
                af[i]  = *(const bf16x8*)(const void*)(&As[rowa * 64 + ca]);
                bfr[i] = *(const bf16x8*)(const void*)(&Bs[rowb * 64 + ca]);
            }
#pragma unroll
            for (int i = 0; i < 4; ++i)
#pragma unroll
                for (int jj = 0; jj < 4; ++jj)
                    acc[i][jj] = __builtin_amdgcn_mfma_f32_16x16x32_bf16(
                        af[i], bfr[jj], acc[i][jj], 0, 0, 0);
        }
        __syncthreads();   // LDS consumed; next kt may overwrite
    }

    // ---- epilogue (C/D layout: col=lane&15, row=quad*4+reg) ----
    if (!OG_EPI) {
        // stage bf16 tile 128x128 in smem, then coalesced 16B stores
        u16* Cs = smem;
#pragma unroll
        for (int i = 0; i < 4; ++i) {
            const int lrow0 = wm * 64 + i * 16 + quad * 4;
#pragma unroll
            for (int jj = 0; jj < 4; ++jj) {
                const int col = wn * 64 + jj * 16 + l15;
#pragma unroll
                for (int r = 0; r < 4; ++r)
                    Cs[(lrow0 + r) * 128 + col] = f2bf(acc[i][jj][r]);
            }
        }
        __syncthreads();
#pragma unroll
        for (int p = 0; p < 8; ++p) {
            const int row = p * 16 + (tid >> 4);
            const int ch16 = tid & 15;
            uint4 v = *(const uint4*)(const void*)(&Cs[row * 128 + ch16 * 8]);
            *(uint4*)(void*)(Gout + (size_t)(m0 + row) * N + n0 + ch16 * 8) = v;
        }
    } else {
        // fp32 out with sigmoid(x+b)*cell; stage 64 rows at a time
        float* Cf = (float*)smem;           // 64 x 128 fp32 = 32 KB
        const int col4 = (tid & 31) * 4;    // output col group for write pass
        float4 b4 = *(const float4*)(const void*)(bias + n0 + col4);
#pragma unroll
        for (int half = 0; half < 2; ++half) {
            if (wm == half) {
#pragma unroll
                for (int i = 0; i < 4; ++i) {
                    const int lrow0 = i * 16 + quad * 4;
#pragma unroll
                    for (int jj = 0; jj < 4; ++jj) {
                        const int col = wn * 64 + jj * 16 + l15;
#pragma unroll
                        for (int r = 0; r < 4; ++r)
                            Cf[(lrow0 + r) * 128 + col] = acc[i][jj][r];
                    }
                }
            }
            __syncthreads();
#pragma unroll
            for (int q = 0; q < 8; ++q) {
                const int lrow = q * 8 + (tid >> 5);
                const int grow = m0 + half * 64 + lrow;
                float4 v = *(const float4*)(const void*)(&Cf[lrow * 128 + col4]);
                const u16* cp = cellbuf + (size_t)grow * K_ + 256 + n0 + col4;
                float4 o;
                o.x = sigm(v.x + b4.x) * bf2f(cp[0]);
                o.y = sigm(v.y + b4.y) * bf2f(cp[1]);
                o.z = sigm(v.z + b4.z) * bf2f(cp[2]);
                o.w = sigm(v.w + b4.w) * bf2f(cp[3]);
                *(float4*)(void*)(Out + (size_t)grow * N2_ + n0 + col4) = o;
            }
            __syncthreads();
        }
    }
}

// ---- scan phase 1: local recurrence over 64 steps; 2 outputs/thread ----
// grid: B*H*16 blocks x 256 thr (each block covers 2 chunks)
__global__ __launch_bounds__(256) void scan_phase1(
    const u16* __restrict__ g, const float* __restrict__ bhid,
    float* __restrict__ cF, float* __restrict__ cC)
{
    const int blk = blockIdx.x;              // (b*8+h)*16 + chp
    const int chp = blk & 15, bh = blk >> 4;
    const int h = bh & 7, b = bh >> 3;
    const int t = threadIdx.x;
    const int ch = chp * 2 + (t >> 7);
    const int o = (t & 127) * 2;
    const float bi0 = bhid[o],       bi1 = bhid[o + 1];
    const float bf0 = bhid[256 + o], bf1 = bhid[257 + o];
    const float bh0 = bhid[512 + o], bh1 = bhid[513 + o];
    float F0 = 1.f, F1 = 1.f, c0 = 0.f, c1 = 0.f;
    for (int i = 0; i < 64; ++i) {
        const int s = ch * 64 + i;
        const size_t m = ((size_t)(b * S_ + s)) * H_ + h;
        const u16* gp = g + m * N1_;
        const u32 igp = *(const u32*)(const void*)(gp + o);
        const u32 fgp = *(const u32*)(const void*)(gp + 256 + o);
        const u32 hdp = *(const u32*)(const void*)(gp + 512 + o);
        const float f0 = sigm(bf2f((u16)fgp) + bf0);
        const float f1 = sigm(bf2f((u16)(fgp >> 16)) + bf1);
        const float i0 = sigm(bf2f((u16)igp) + bi0) * fmaxf(bf2f((u16)hdp) + bh0, 0.f);
        const float i1 = sigm(bf2f((u16)(igp >> 16)) + bi1) * fmaxf(bf2f((u16)(hdp >> 16)) + bh1, 0.f);
        c0 = f0 * c0 + i0;  F0 *= f0;
        c1 = f1 * c1 + i1;  F1 *= f1;
    }
    const size_t idx = ((size_t)(bh * 32 + ch)) * 256 + o;
    cF[idx] = F0; cF[idx + 1] = F1;
    cC[idx] = c0; cC[idx + 1] = c1;
}

// ---- scan carry combine ----
__global__ __launch_bounds__(256) void scan_mid(
    const float* __restrict__ cF, const float* __restrict__ cC,
    const float* __restrict__ initcx, float* __restrict__ cin)
{
    const int bh = blockIdx.x;               // b*8 + h
    const int h = bh & 7;
    const int o = threadIdx.x;
    float c = initcx[h * 256 + o];
    for (int ch = 0; ch < 32; ++ch) {
        const size_t idx = ((size_t)(bh * 32 + ch)) * 256 + o;
        cin[idx] = c;
        c = cF[idx] * c + cC[idx];
    }
}

// ---- scan phase 2: replay; write cell bf16 into x2 cols [256,512) ----
__global__ __launch_bounds__(256) void scan_phase2(
    const u16* __restrict__ g, const float* __restrict__ bhid,
    const float* __restrict__ cin, u16* __restrict__ x2)
{
    const int blk = blockIdx.x;
    const int chp = blk & 15, bh = blk >> 4;
    const int h = bh & 7, b = bh >> 3;
    const int t = threadIdx.x;
    const int ch = chp * 2 + (t >> 7);
    const int o = (t & 127) * 2;
    const float bi0 = bhid[o],       bi1 = bhid[o + 1];
    const float bf0 = bhid[256 + o], bf1 = bhid[257 + o];
    const float bh0 = bhid[512 + o], bh1 = bhid[513 + o];
    const size_t idx = ((size_t)(bh * 32 + ch)) * 256 + o;
    float c0 = cin[idx], c1 = cin[idx + 1];
    for (int i = 0; i < 64; ++i) {
        const int s = ch * 64 + i;
        const size_t m = ((size_t)(b * S_ + s)) * H_ + h;
        const u16* gp = g + m * N1_;
        const u32 igp = *(const u32*)(const void*)(gp + o);
        const u32 fgp = *(const u32*)(const void*)(gp + 256 + o);
        const u32 hdp = *(const u32*)(const void*)(gp + 512 + o);
        const float f0 = sigm(bf2f((u16)fgp) + bf0);
        const float f1 = sigm(bf2f((u16)(fgp >> 16)) + bf1);
        const float i0 = sigm(bf2f((u16)igp) + bi0) * fmaxf(bf2f((u16)hdp) + bh0, 0.f);
        const float i1 = sigm(bf2f((u16)(igp >> 16)) + bi1) * fmaxf(bf2f((u16)(hdp >> 16)) + bh1, 0.f);
        c0 = f0 * c0 + i0;
        c1 = f1 * c1 + i1;
        const u32 pk = (u32)f2bf(c0) | ((u32)f2bf(c1) << 16);
        *(u32*)(void*)(x2 + m * K_ + 256 + o) = pk;
    }
}

extern "C" void kernel_launch(void* const* d_in, const int* in_sizes, int n_in,
                              void* d_out, int out_size, void* d_ws, size_t ws_size,
                              hipStream_t stream)
{
    const float* X      = (const float*)d_in[0];
    const float* Whid   = (const float*)d_in[1];
    const float* bhid   = (const float*)d_in[2];
    const float* Wog    = (const float*)d_in[3];
    const float* bog    = (const float*)d_in[4];
    const float* lnw    = (const float*)d_in[5];
    const float* lnb    = (const float*)d_in[6];
    const float* initcx = (const float*)d_in[7];
    float* out = (float*)d_out;

    char* ws = (char*)d_ws;
    u16* x2   = (u16*)(ws + OFF_X2);
    u16* g    = (u16*)(ws + OFF_G);
    u16* WhB  = (u16*)(ws + OFF_WH);
    u16* WoB  = (u16*)(ws + OFF_WO);
    float* aux = (float*)(ws + OFF_AUX);
    float* cF  = (float*)(ws + OFF_CF);
    float* cC  = (float*)(ws + OFF_CC);
    float* cin = (float*)(ws + OFF_CIN);

    wconv_kernel<<<(N1_*K_ + 255) / 256, 256, 0, stream>>>(Whid, Wog, WhB, WoB);
    csum_phase1<<<B_ * CSCH, 256, 0, stream>>>(X, aux);
    csum_mid<<<64, 256, 0, stream>>>(aux);
    csum_phase2<<<B_ * CSCH, 256, 0, stream>>>(X, aux, lnw, lnb, x2);
    gemm_kernel<N1_, false><<<(M_ / 128) * (N1_ / 128), 256, 0, stream>>>(
        x2, WhB, g, nullptr, nullptr, nullptr);
    scan_phase1<<<B_ * H_ * 16, 256, 0, stream>>>(g, bhid, cF, cC);
    scan_mid<<<B_ * H_, 256, 0, stream>>>(cF, cC, initcx, cin);
    scan_phase2<<<B_ * H_ * 16, 256, 0, stream>>>(g, bhid, cin, x2);
    gemm_kernel<N2_, true><<<(M_ / 128) * (N2_ / 128), 256, 0, stream>>>(
        x2, WoB, nullptr, bog, x2, out);
}